// Round 10
// baseline (368.332 us; speedup 1.0000x reference)
//
#include <hip/hip_runtime.h>
#include <hip/hip_bf16.h>

// KroneckerMixer: B=64, N=1024, K=64, BASIS=8, T=0.2, 20 sinkhorn iters.
// R10 pipeline (bf16 path, ws >= 36.5 MB):
//   k_front : fused, grid 272 x 1024 (16 sinkA + 256 wpath blocks; the 16
//             extra blocks double up on CUs, 2x71.7KB LDS fits in 160KB).
//     Blocks 0..15 = A-sinkhorn u/v solver, E register-resident (e4[4][4]).
//       Row pass reads v from PERMUTED LDS layout v4s[q*64+lane] (16B lane
//       stride, conflict-free b128) — R7/R9's v_s[lane*16+..] 64B-stride read
//       was the 1.8M-cycle bank-conflict source. Col exchange via cps2 +
//       sc1 ping-pong P + flat 16-way relaxed barrier (R9-verified).
//     Blocks 16..271 = W-path: 4 CONCURRENT 256-thread groups per block, one
//       n each (R3-verified 256-thread body; lockstep through shared syncs).
//       Serial depth 20 iters/CU, not 80 (R9's sequential n's = 49us/n).
//       Matmul reads x from global (L1 broadcast), Ws-only LDS per group.
//   k_xt    : transpose + v-scale + hi/lo split XL -> XTh/XTl bf16 [c][n].
//   k_gemm3 : out[m][c] = u_m*(Eh*XTh + El*XTh + Eh*XTl), 16x16x32 bf16 MFMA,
//             tile 128x64, grid (8,64) = 2 blocks/CU (unchanged from R9).
// Fallback (small ws): fp32 k_gemm with u/v folded.

#define N_DIM 1024
#define INV_T 5.0f
#define NBAR 16  // A-sinkhorn barrier blocks

typedef __attribute__((ext_vector_type(8))) short short8;
typedef __attribute__((ext_vector_type(4))) float float4v;

// ---------------- wave64 sum reduction via DPP (VALU pipe) -------------------
// Result valid in lane 63.
__device__ __forceinline__ float wave_red_sum(float x) {
#define DPP_ADD(C)                                                            \
  {                                                                           \
    int _y = __builtin_amdgcn_update_dpp(0, __float_as_int(x), (C), 0xf, 0xf, \
                                         true);                               \
    x += __int_as_float(_y);                                                  \
  }
  DPP_ADD(0x111);
  DPP_ADD(0x112);
  DPP_ADD(0x114);
  DPP_ADD(0x118);
  DPP_ADD(0x142);
  DPP_ADD(0x143);
#undef DPP_ADD
  return x;
}

// ---- flat 16-way grid barrier, monotonic, fully relaxed (sc1 counters) ------
// ctrl: gen@word0, cnt@word32 (separate lines, 4096 B zeroed). bi = 0..19.
__device__ __forceinline__ void gbar3(unsigned* ctrl, int bi) {
  __syncthreads();
  if (threadIdx.x == 0) {
    unsigned* gen = ctrl;
    unsigned* cnt = ctrl + 32;
    unsigned a = __hip_atomic_fetch_add(cnt, 1u, __ATOMIC_RELAXED,
                                        __HIP_MEMORY_SCOPE_AGENT);
    if (a == (unsigned)bi * (unsigned)NBAR + (unsigned)(NBAR - 1)) {
      __hip_atomic_fetch_add(gen, 1u, __ATOMIC_RELAXED,
                             __HIP_MEMORY_SCOPE_AGENT);
    } else {
      while (__hip_atomic_load(gen, __ATOMIC_RELAXED,
                               __HIP_MEMORY_SCOPE_AGENT) <= (unsigned)bi)
        __builtin_amdgcn_s_sleep(2);
    }
  }
  __syncthreads();
}

// ---------------- kernel 1: fused sinkA(u,v) + wpath -------------------------
// grid 272 x 1024. smem: sinkA {v4s 256 f4, cps2 4096 f4} = 17408 floats;
// wpath {4 groups x (Ws 64*65=4160, uS2 64, ps 256) = 4480} = 17920 floats.
__global__ __launch_bounds__(1024) void k_front(
    const float* __restrict__ x, const float* __restrict__ L,
    const float* __restrict__ W1, const float* __restrict__ WV,
    float* __restrict__ E0, __hip_bfloat16* __restrict__ Eh,
    __hip_bfloat16* __restrict__ El, float* __restrict__ P,
    unsigned* __restrict__ ctrl, float* __restrict__ u_g,
    float* __restrict__ v_g, float* __restrict__ XL, int write_bf16) {
  __shared__ __align__(16) float smem[17920];
  const int t = threadIdx.x;
  const int bid = blockIdx.x;
  const int lane = t & 63;
  const int w = t >> 6;  // 0..15

  if (bid < NBAR) {
    // =================== A-sinkhorn u/v role (E in registers) ===============
    // v permuted: v4s[q*64 + l] holds v[l*16 + 4q .. +3]  (conflict-free read)
    float4* v4s = (float4*)smem;             // 256 float4
    float4* cps2 = (float4*)(smem + 1024);   // 4096 float4
    const int r0 = bid * 64;

    float4 e4[4][4];  // e4[row j][quad q]: rows r0+4w+j, cols lane*16+4q..
    float p[4];
    // ---- iter-0 row pass fused with E materialization
#pragma unroll
    for (int j = 0; j < 4; ++j) {
      const int r = r0 + 4 * w + j;
      const float4* Lr = (const float4*)(L + (size_t)r * N_DIM + lane * 16);
      float pj = 0.f;
#pragma unroll
      for (int q = 0; q < 4; ++q) {
        float4 f = Lr[q];
        float4 g;
        g.x = __expf(f.x * INV_T);
        g.y = __expf(f.y * INV_T);
        g.z = __expf(f.z * INV_T);
        g.w = __expf(f.w * INV_T);
        e4[j][q] = g;
        pj += (g.x + g.y) + (g.z + g.w);
      }
      p[j] = pj;
      const size_t off = (size_t)r * N_DIM + lane * 16;
      if (write_bf16) {
        __align__(16) ushort hb[16], lb[16];
#pragma unroll
        for (int q = 0; q < 4; ++q) {
          const float ev[4] = {e4[j][q].x, e4[j][q].y, e4[j][q].z, e4[j][q].w};
#pragma unroll
          for (int z = 0; z < 4; ++z) {
            __hip_bfloat16 h = __float2bfloat16(ev[z]);
            hb[4 * q + z] = *(ushort*)&h;
            __hip_bfloat16 l = __float2bfloat16(ev[z] - __bfloat162float(h));
            lb[4 * q + z] = *(ushort*)&l;
          }
        }
        *(uint4*)&Eh[off] = *(uint4*)&hb[0];
        *(uint4*)&Eh[off + 8] = *(uint4*)&hb[8];
        *(uint4*)&El[off] = *(uint4*)&lb[0];
        *(uint4*)&El[off + 8] = *(uint4*)&lb[8];
      } else {
        float4* Er = (float4*)(E0 + off);
#pragma unroll
        for (int q = 0; q < 4; ++q) Er[q] = e4[j][q];
      }
    }

    float u_j[4];
    float vmine = 1.0f;
    for (int it = 0; it < 20; ++it) {
      // ---- row pass (it>0): p_j = sum_c e[j][c]*v[c]; v4s conflict-free
      if (it > 0) {
#pragma unroll
        for (int j = 0; j < 4; ++j) {
          float pj = 0.f;
#pragma unroll
          for (int q = 0; q < 4; ++q) {
            float4 vv = v4s[q * 64 + lane];
            float4 e = e4[j][q];
            pj += e.x * vv.x + e.y * vv.y + e.z * vv.z + e.w * vv.w;
          }
          p[j] = pj;
        }
      }
#pragma unroll
      for (int j = 0; j < 4; ++j) {
        float pr = wave_red_sum(p[j]);
        u_j[j] = 1.0f / __shfl(pr, 63);  // wave-uniform broadcast
      }
      // ---- col partials: cps2[(w*4+q)*64 + lane] (16B lane stride, clean)
#pragma unroll
      for (int q = 0; q < 4; ++q) {
        float4 cp;
        cp.x = e4[0][q].x * u_j[0] + e4[1][q].x * u_j[1] +
               e4[2][q].x * u_j[2] + e4[3][q].x * u_j[3];
        cp.y = e4[0][q].y * u_j[0] + e4[1][q].y * u_j[1] +
               e4[2][q].y * u_j[2] + e4[3][q].y * u_j[3];
        cp.z = e4[0][q].z * u_j[0] + e4[1][q].z * u_j[1] +
               e4[2][q].z * u_j[2] + e4[3][q].z * u_j[3];
        cp.w = e4[0][q].w * u_j[0] + e4[1][q].w * u_j[1] +
               e4[2][q].w * u_j[2] + e4[3][q].w * u_j[3];
        cps2[(w * 4 + q) * 64 + lane] = cp;
      }
      __syncthreads();
      // ---- cross-wave reduce: thread t owns col t
      //      col t: lr = t>>4, qr = (t>>2)&3, zr = t&3
      {
        const int lr = t >> 4, qr = (t >> 2) & 3, zr = t & 3;
        float s = 0.f;
#pragma unroll
        for (int ww = 0; ww < 16; ++ww)
          s += ((const float*)&cps2[(ww * 4 + qr) * 64 + lr])[zr];
        float* Pw = P + (it & 1) * (NBAR * N_DIM);
        __hip_atomic_store(&Pw[bid * N_DIM + t], s, __ATOMIC_RELAXED,
                           __HIP_MEMORY_SCOPE_AGENT);
        gbar3(ctrl, it);
        // ---- v update: 16 sc1 loads per thread; scatter into permuted v4s
        float s2 = 0.f;
#pragma unroll
        for (int pb = 0; pb < NBAR; ++pb)
          s2 += __hip_atomic_load(&Pw[pb * N_DIM + t], __ATOMIC_RELAXED,
                                  __HIP_MEMORY_SCOPE_AGENT);
        vmine = 1.0f / s2;
        smem[qr * 256 + lr * 4 + zr] = vmine;  // v4s scatter (4-way, cheap)
      }
      __syncthreads();
    }
    // ---- epilogue: u (lane 0 per wave), v (block 0, own register)
    if (lane == 0) {
#pragma unroll
      for (int j = 0; j < 4; ++j) u_g[r0 + 4 * w + j] = u_j[j];
    }
    if (bid == 0) v_g[t] = vmine;
  } else {
    // ============ W-path role: 4 CONCURRENT groups of 256 threads ===========
    const int g = t >> 8;     // group 0..3
    const int tl = t & 255;   // group-local thread
    const int h = tl >> 6;    // group-local wave 0..3
    const int n = (bid - NBAR) * 4 + g;
    float* Ws = smem + g * 4480;          // [64*65]
    float* uS2 = smem + g * 4480 + 4160;  // [64]
    float* ps = smem + g * 4480 + 4224;   // [4][64]

    float w1[8];
#pragma unroll
    for (int k = 0; k < 8; ++k) w1[k] = W1[n * 8 + k];

    // element f = j*256 + tl -> row i = 4j+h, col o = lane
    float ew[16];
#pragma unroll
    for (int j = 0; j < 16; ++j) {
      const int f = j * 256 + tl;
      float acc = 0.f;
#pragma unroll
      for (int k = 0; k < 8; ++k) acc += w1[k] * WV[k * 4096 + f];
      ew[j] = __expf(acc * INV_T);
    }

    float vt = 1.0f;
    for (int it = 0; it < 20; ++it) {
      // row pass: wave h owns rows 4j+h entirely (64 cols = 64 lanes)
#pragma unroll
      for (int j = 0; j < 16; ++j) {
        float pp = wave_red_sum(ew[j] * vt);
        if (lane == 63) uS2[4 * j + h] = 1.0f / pp;
      }
      // uS2[4j+h] written & read by the same wave: in-order LDS pipe (R3-ok)
      float cp = 0.f;
#pragma unroll
      for (int j = 0; j < 16; ++j) cp += ew[j] * uS2[4 * j + h];
      ps[h * 64 + lane] = cp;
      __syncthreads();  // all 4 groups in lockstep (symmetric work)
      vt = 1.0f / (ps[0 * 64 + lane] + ps[1 * 64 + lane] + ps[2 * 64 + lane] +
                   ps[3 * 64 + lane]);
      __syncthreads();
    }

    // materialize W into LDS (stride 65 for conflict-free b128 reads)
#pragma unroll
    for (int j = 0; j < 16; ++j)
      Ws[(4 * j + h) * 65 + lane] = ew[j] * uS2[4 * j + h] * vt;
    __syncthreads();

    // x_local[b][o] = sum_i x[b][n*64+i] * W[i][o]; thread tile 4b x 4o.
    // x read from global as float4 (L1 broadcast across the 16 same-b lanes).
    const int b4 = (tl >> 4) * 4;
    const int o4 = (tl & 15) * 4;
    const float4* x4 = (const float4*)x;
    float4 acc[4];
#pragma unroll
    for (int bb = 0; bb < 4; ++bb) acc[bb] = (float4){0.f, 0.f, 0.f, 0.f};
#pragma unroll 4
    for (int q = 0; q < 16; ++q) {
      float4 xq[4];
#pragma unroll
      for (int bb = 0; bb < 4; ++bb)
        xq[bb] = x4[(size_t)(b4 + bb) * 16384 + n * 16 + q];
#pragma unroll
      for (int z = 0; z < 4; ++z) {
        const int i = 4 * q + z;
        float4 w4 = *(const float4*)&Ws[i * 65 + o4];
#pragma unroll
        for (int bb = 0; bb < 4; ++bb) {
          const float xs = ((const float*)&xq[bb])[z];
          acc[bb].x += xs * w4.x;
          acc[bb].y += xs * w4.y;
          acc[bb].z += xs * w4.z;
          acc[bb].w += xs * w4.w;
        }
      }
    }
#pragma unroll
    for (int bb = 0; bb < 4; ++bb)
      *(float4*)&XL[(size_t)n * 4096 + (b4 + bb) * 64 + o4] = acc[bb];
  }
}

// ---------------- kernel 2b: transpose + v-scale + hi/lo split ---------------
// XTh/XTl[c][n] = hi/lo bf16 of (v[n] * XL[n][c]).
__global__ __launch_bounds__(256) void k_xt(const float* __restrict__ XL,
                                            const float* __restrict__ v_g,
                                            __hip_bfloat16* __restrict__ XTh,
                                            __hip_bfloat16* __restrict__ XTl) {
  __shared__ float T[64 * 68];
  __shared__ float vsh[64];
  const int t = threadIdx.x;
  const int n0 = blockIdx.x * 64;
  const int c0 = blockIdx.y * 64;
  if (t < 64) vsh[t] = v_g[n0 + t];
  {
    const int r = t >> 4;         // 0..15
    const int c4 = (t & 15) * 4;  // 0..60
#pragma unroll
    for (int p = 0; p < 4; ++p) {
      float4 f =
          *(const float4*)&XL[(size_t)(n0 + r + 16 * p) * 4096 + c0 + c4];
      *(float4*)&T[(r + 16 * p) * 68 + c4] = f;
    }
  }
  __syncthreads();
  const int cl = t >> 2;        // 0..63
  const int nb = (t & 3) * 16;  // 0,16,32,48
  __align__(16) __hip_bfloat16 hbuf[16];
  __align__(16) __hip_bfloat16 lbuf[16];
#pragma unroll
  for (int j = 0; j < 16; ++j) {
    float xv = T[(nb + j) * 68 + cl] * vsh[nb + j];
    __hip_bfloat16 h = __float2bfloat16(xv);
    hbuf[j] = h;
    lbuf[j] = __float2bfloat16(xv - __bfloat162float(h));
  }
  const size_t off = (size_t)(c0 + cl) * 1024 + n0 + nb;
  *(uint4*)&XTh[off] = *(uint4*)&hbuf[0];
  *(uint4*)&XTh[off + 8] = *(uint4*)&hbuf[8];
  *(uint4*)&XTl[off] = *(uint4*)&lbuf[0];
  *(uint4*)&XTl[off + 8] = *(uint4*)&lbuf[8];
}

// ---------------- kernel 3 (bf16): out = u ⊙ (Eh*XTh + El*XTh + Eh*XTl) ------
// Tile 128m x 64c, grid (8,64) = 512 blocks = 2 blocks/CU (TLP hides barrier
// drain). 4 waves: wave (wid&1) -> m-half, (wid>>1) -> c-half of 64x32.
#define LSTR 72  // padded LDS row stride (elements)
__global__ __launch_bounds__(256) void k_gemm3(
    const ushort* __restrict__ Eh, const ushort* __restrict__ El,
    const ushort* __restrict__ XTh, const ushort* __restrict__ XTl,
    const float* __restrict__ u_g, float* __restrict__ out) {
  __shared__ ushort As[128 * LSTR];  // 18432 B
  __shared__ ushort Xs[64 * LSTR];   // 9216 B
  __shared__ float ush[128];
  const int t = threadIdx.x;
  const int m0 = blockIdx.x * 128;
  const int c0 = blockIdx.y * 64;
  const int wid = t >> 6, lane = t & 63;
  const int wm = (wid & 1) * 64, wc = (wid >> 1) * 32;
  const int lm = lane & 15, q = lane >> 4;
  const int sra = t >> 1;        // A staging row 0..127
  const int sca = (t & 1) * 32;  // A staging k-offset: [sca, sca+32)
  const int srx = t >> 2;        // X staging row 0..63
  const int scx = (t & 3) * 16;  // X staging k-offset: [scx, scx+16)
  if (t < 128) ush[t] = u_g[m0 + t];

  float4v acc[4][2];
#pragma unroll
  for (int i = 0; i < 4; ++i)
#pragma unroll
    for (int j = 0; j < 2; ++j) acc[i][j] = (float4v){0.f, 0.f, 0.f, 0.f};

  for (int seg = 0; seg < 3; ++seg) {
    const ushort* Ag = (seg == 1) ? El : Eh;
    const ushort* Xg = (seg == 2) ? XTl : XTh;
    for (int k0 = 0; k0 < 1024; k0 += 64) {
      __syncthreads();
      const ushort* ag = Ag + (size_t)(m0 + sra) * 1024 + k0 + sca;
      const ushort* xg = Xg + (size_t)(c0 + srx) * 1024 + k0 + scx;
      uint4 a0 = *(const uint4*)(ag);
      uint4 a1 = *(const uint4*)(ag + 8);
      uint4 a2 = *(const uint4*)(ag + 16);
      uint4 a3 = *(const uint4*)(ag + 24);
      uint4 x0 = *(const uint4*)(xg);
      uint4 x1 = *(const uint4*)(xg + 8);
      *(uint4*)&As[sra * LSTR + sca] = a0;
      *(uint4*)&As[sra * LSTR + sca + 8] = a1;
      *(uint4*)&As[sra * LSTR + sca + 16] = a2;
      *(uint4*)&As[sra * LSTR + sca + 24] = a3;
      *(uint4*)&Xs[srx * LSTR + scx] = x0;
      *(uint4*)&Xs[srx * LSTR + scx + 8] = x1;
      __syncthreads();
#pragma unroll
      for (int kk = 0; kk < 2; ++kk) {
        short8 af[4], xf[2];
#pragma unroll
        for (int i = 0; i < 4; ++i)
          af[i] = *(const short8*)&As[(wm + 16 * i + lm) * LSTR + kk * 32 +
                                      q * 8];
#pragma unroll
        for (int j = 0; j < 2; ++j)
          xf[j] = *(const short8*)&Xs[(wc + 16 * j + lm) * LSTR + kk * 32 +
                                      q * 8];
#pragma unroll
        for (int i = 0; i < 4; ++i)
#pragma unroll
          for (int j = 0; j < 2; ++j)
            acc[i][j] = __builtin_amdgcn_mfma_f32_16x16x32_bf16(
                af[i], xf[j], acc[i][j], 0, 0, 0);
      }
    }
  }
  // epilogue: D row = q*4 + reg, col = lm (m89-verified); scale by u_m
#pragma unroll
  for (int i = 0; i < 4; ++i) {
#pragma unroll
    for (int j = 0; j < 2; ++j) {
      const int ml = wm + 16 * i + q * 4;
      const int m = m0 + ml;
      const int c = c0 + wc + 16 * j + lm;
      const int bb = c >> 6, o = c & 63;
      float* dst = out + (size_t)bb * 65536 + (size_t)m * 64 + o;
#pragma unroll
      for (int r = 0; r < 4; ++r) dst[64 * r] = acc[i][j][r] * ush[ml + r];
    }
  }
}

// ---------------- kernel 3 (fp32 fallback): out = u ⊙ (E0·(v⊙XL)) ------------
__global__ __launch_bounds__(256) void k_gemm(const float* __restrict__ E0,
                                              const float* __restrict__ XL,
                                              const float* __restrict__ u_g,
                                              const float* __restrict__ v_g,
                                              float* __restrict__ out) {
  __shared__ float Asm[32][132];
  __shared__ float Xsm[32][132];
  const int t = threadIdx.x;
  const int m0 = blockIdx.x * 128;
  const int c0 = blockIdx.y * 128;
  const int my8 = (t >> 4) * 8;
  const int cx8 = (t & 15) * 8;
  const int kk = t & 31;
  const int rr = t >> 5;
  float acc[8][8] = {};

  for (int k0 = 0; k0 < 1024; k0 += 32) {
#pragma unroll
    for (int s = 0; s < 16; ++s)
      Asm[kk][rr + 8 * s] = E0[(size_t)(m0 + rr + 8 * s) * 1024 + k0 + kk];
#pragma unroll
    for (int s = 0; s < 4; ++s) {
      const int krow = k0 + rr + 8 * s;
      float vk = v_g[krow];
      float4 f = *(const float4*)&XL[(size_t)krow * 4096 + c0 + kk * 4];
      f.x *= vk;
      f.y *= vk;
      f.z *= vk;
      f.w *= vk;
      *(float4*)&Xsm[rr + 8 * s][kk * 4] = f;
    }
    __syncthreads();
#pragma unroll
    for (int k = 0; k < 32; ++k) {
      float a[8], xv[8];
      *(float4*)&a[0] = *(const float4*)&Asm[k][my8];
      *(float4*)&a[4] = *(const float4*)&Asm[k][my8 + 4];
      *(float4*)&xv[0] = *(const float4*)&Xsm[k][cx8];
      *(float4*)&xv[4] = *(const float4*)&Xsm[k][cx8 + 4];
#pragma unroll
      for (int i = 0; i < 8; ++i)
#pragma unroll
        for (int j = 0; j < 8; ++j) acc[i][j] += a[i] * xv[j];
    }
    __syncthreads();
  }

#pragma unroll
  for (int i = 0; i < 8; ++i) {
    const int m = m0 + my8 + i;
    const float um = u_g[m];
    const int c = c0 + cx8;
    const int bb = c >> 6, o = c & 63;
    float* dst = out + (size_t)bb * 65536 + (size_t)m * 64 + o;
#pragma unroll
    for (int j = 0; j < 8; ++j) dst[j] = acc[i][j] * um;
  }
}

// ---------------- launcher ---------------------------------------------------
extern "C" void kernel_launch(void* const* d_in, const int* in_sizes, int n_in,
                              void* d_out, int out_size, void* d_ws,
                              size_t ws_size, hipStream_t stream) {
  (void)in_sizes;
  (void)n_in;
  (void)out_size;
  const float* x = (const float*)d_in[0];
  const float* Alog = (const float*)d_in[1];
  const float* W1 = (const float*)d_in[2];
  const float* WV = (const float*)d_in[3];
  float* out = (float*)d_out;

  char* ws = (char*)d_ws;
  const size_t MB = 1024 * 1024;
  const size_t KB = 1024;
  const bool use_bf16 = ws_size >= (36 * MB + 512 * KB);

  float* E0;
  float* XL;
  float* P;
  float* u_g;
  float* v_g;
  unsigned* ctrl;
  __hip_bfloat16 *Eh = nullptr, *El = nullptr, *XTh = nullptr, *XTl = nullptr;
  if (use_bf16) {
    Eh = (__hip_bfloat16*)(ws);             // 2 MB
    El = (__hip_bfloat16*)(ws + 2 * MB);    // 2 MB
    XTh = (__hip_bfloat16*)(ws + 4 * MB);   // 8 MB
    XTl = (__hip_bfloat16*)(ws + 12 * MB);  // 8 MB
    XL = (float*)(ws + 20 * MB);            // 16 MB -> ends 36 MB
    P = (float*)(ws + 36 * MB);             // 128 KB (2x ping-pong)
    u_g = (float*)(ws + 36 * MB + 128 * KB);
    v_g = (float*)(ws + 36 * MB + 132 * KB);
    ctrl = (unsigned*)(ws + 36 * MB + 136 * KB);  // 4 KB zeroed
    E0 = (float*)ws;                              // unused in bf16 mode
  } else {
    E0 = (float*)(ws);           // 4 MB
    XL = (float*)(ws + 4 * MB);  // 16 MB
    P = (float*)(ws + 20 * MB);  // 128 KB
    u_g = (float*)(ws + 20 * MB + 128 * KB);
    v_g = (float*)(ws + 20 * MB + 132 * KB);
    ctrl = (unsigned*)(ws + 20 * MB + 136 * KB);
  }

  (void)hipMemsetAsync(ctrl, 0, 4096, stream);  // covers all barrier counters
  hipLaunchKernelGGL(k_front, dim3(NBAR + 256), dim3(1024), 0, stream, x, Alog,
                     W1, WV, E0, Eh, El, P, ctrl, u_g, v_g, XL,
                     use_bf16 ? 1 : 0);
  if (use_bf16) {
    hipLaunchKernelGGL(k_xt, dim3(16, 64), dim3(256), 0, stream, XL, v_g, XTh,
                       XTl);
    hipLaunchKernelGGL(k_gemm3, dim3(8, 64), dim3(256), 0, stream,
                       (const ushort*)Eh, (const ushort*)El, (const ushort*)XTh,
                       (const ushort*)XTl, u_g, out);
  } else {
    hipLaunchKernelGGL(k_gemm, dim3(8, 32), dim3(256), 0, stream, E0, XL, u_g,
                       v_g, out);
  }
}